// Round 15
// baseline (2661.208 us; speedup 1.0000x reference)
//
#include <hip/hip_runtime.h>
#include <math.h>

#define BB 2
#define LL 4096
#define DMODEL 512
#define DINNER 1024
#define DHALF 512
#define DSTATE 16
#define RK 32
#define NCH 64          // x_dbl channels (32 dt + 16 B + 16 C)
#define NC 256          // scan chunks
#define CLEN (LL/NC)    // 16
#define LOG2E 1.44269504088896f

typedef __attribute__((ext_vector_type(8))) short short8;
typedef __attribute__((ext_vector_type(4))) float f32x4;

__device__ __forceinline__ float silu_f(float v) { return v / (1.f + __expf(-v)); }

// round-to-nearest-even fp32 -> bf16 (inputs finite)
__device__ __forceinline__ unsigned short f2bf(float x) {
    unsigned int u = __float_as_uint(x);
    u += 0x7fffu + ((u >> 16) & 1u);
    return (unsigned short)(u >> 16);
}
__device__ __forceinline__ float bf2f(unsigned short u) {
    return __uint_as_float((unsigned int)u << 16);
}

__device__ __forceinline__ float softplus_f(float x) {
    return fmaxf(x, 0.f) + __logf(1.f + __expf(-fabsf(x)));
}

// raw v_exp_f32 (base-2), no libm guards
__device__ __forceinline__ float exp2_raw(float x) { return __builtin_amdgcn_exp2f(x); }

__device__ __forceinline__ void gload16(const unsigned short* g, unsigned short* l) {
    __builtin_amdgcn_global_load_lds((const __attribute__((address_space(1))) void*)g,
                                     (__attribute__((address_space(3))) void*)l, 16, 0, 0);
}

// ---------------- cast kernel: fp32->bf16 for H/W1/W2/Wx, plus Arow2T precompute --------
#define H4  1048576   // hidden vec4 count
#define W14 131072    // in_proj
#define W24 131072    // out_proj
#define W34 8192      // x_proj
#define NA  8192      // Arow2T elements (16 x 512)
__global__ void cast_all(const float* __restrict__ hid, const float* __restrict__ w1,
                         const float* __restrict__ w2, const float* __restrict__ w3,
                         const float* __restrict__ A_log,
                         unsigned short* __restrict__ Hb, unsigned short* __restrict__ Wb,
                         unsigned short* __restrict__ Wob, unsigned short* __restrict__ Wxb,
                         float* __restrict__ Arow2T) {
    int i = blockIdx.x * 256 + threadIdx.x;
    if (i >= H4 + W14 + W24 + W34) {
        int j = i - (H4 + W14 + W24 + W34);
        if (j < NA) {
            int n = j >> 9, d = j & 511;
            Arow2T[j] = -expf(A_log[d * DSTATE + n]) * LOG2E;   // [n][d] layout
        }
        return;
    }
    const float* src; unsigned short* dst; int j;
    if (i < H4)                    { src = hid; dst = Hb;  j = i; }
    else if (i < H4 + W14)         { src = w1;  dst = Wb;  j = i - H4; }
    else if (i < H4 + W14 + W24)   { src = w2;  dst = Wob; j = i - H4 - W14; }
    else                           { src = w3;  dst = Wxb; j = i - H4 - W14 - W24; }
    float4 v = *(const float4*)&src[(size_t)j * 4];
    ushort4 o = make_ushort4(f2bf(v.x), f2bf(v.y), f2bf(v.z), f2bf(v.w));
    *(ushort4*)&dst[(size_t)j * 4] = o;
}

// ---------------- bf16 MFMA GEMM, 128r x 64e tile ----------------
// W: [E][K] bf16 k-major.  X: [R][K] bf16 k-major.  out[r][e] = sum_k W[e][k]*X[r][k]
template<int K, int E, bool BF16OUT>
__global__ __launch_bounds__(256, 4) void gemm_mfma(const unsigned short* __restrict__ W,
                                                    const unsigned short* __restrict__ X,
                                                    void* __restrict__ outv) {
    __shared__ unsigned short Xa[128 * 64];   // [row][k], 16B-chunk XOR-swizzled
    __shared__ unsigned short Wa[64 * 64];
    const int tid = threadIdx.x;
    const int lane = tid & 63;
    const int w = tid >> 6;
    const int frow = lane & 15;
    const int kg = lane >> 4;
    const int e0 = blockIdx.y * 64;
    const int r0 = blockIdx.x * 128;

    f32x4 acc[4][2] = {};

    for (int kt = 0; kt < K / 64; ++kt) {
        #pragma unroll
        for (int i = 0; i < 4; ++i) {
            int flat = i * 256 + tid;         // 16B units
            int row = flat >> 3;
            int slot = flat & 7;
            int chunk = slot ^ (row & 7);
            gload16(&X[(size_t)(r0 + row) * K + kt * 64 + chunk * 8], &Xa[flat * 8]);
        }
        #pragma unroll
        for (int i = 0; i < 2; ++i) {
            int flat = i * 256 + tid;         // 0..511
            int row = flat >> 3;              // 0..63
            int slot = flat & 7;
            int chunk = slot ^ (row & 7);
            gload16(&W[(size_t)(e0 + row) * K + kt * 64 + chunk * 8], &Wa[flat * 8]);
        }
        __syncthreads();

        #pragma unroll
        for (int ks = 0; ks < 2; ++ks) {
            short8 af[4], bfr[2];
            #pragma unroll
            for (int m = 0; m < 4; ++m) {
                int row = m * 16 + frow;
                int phys = (ks * 4 + kg) ^ (row & 7);
                af[m] = *(const short8*)&Wa[row * 64 + phys * 8];
            }
            #pragma unroll
            for (int n = 0; n < 2; ++n) {
                int row = w * 32 + n * 16 + frow;
                int phys = (ks * 4 + kg) ^ (row & 7);
                bfr[n] = *(const short8*)&Xa[row * 64 + phys * 8];
            }
            #pragma unroll
            for (int m = 0; m < 4; ++m)
                #pragma unroll
                for (int n = 0; n < 2; ++n)
                    acc[m][n] = __builtin_amdgcn_mfma_f32_16x16x32_bf16(af[m], bfr[n], acc[m][n], 0, 0, 0);
        }
        __syncthreads();
    }

    #pragma unroll
    for (int m = 0; m < 4; ++m) {
        #pragma unroll
        for (int n = 0; n < 2; ++n) {
            int e = e0 + m * 16 + kg * 4;
            int r = r0 + w * 32 + n * 16 + frow;
            f32x4 a = acc[m][n];
            if constexpr (BF16OUT) {
                ushort4 o = make_ushort4(f2bf(a.x), f2bf(a.y), f2bf(a.z), f2bf(a.w));
                *(ushort4*)&((unsigned short*)outv)[(size_t)r * E + e] = o;
            } else {
                *(f32x4*)&((float*)outv)[(size_t)r * E + e] = a;
            }
        }
    }
}

// ---------------- x_proj MFMA: 128r x 64e tile, out (b, ch, l) fp32 ----------------
__global__ __launch_bounds__(256) void gemm_xproj(const unsigned short* __restrict__ W,
                                                  const unsigned short* __restrict__ X,
                                                  float* __restrict__ out) {
    __shared__ unsigned short Xa[128 * 64];
    __shared__ unsigned short Wa[64 * 64];
    const int tid = threadIdx.x;
    const int lane = tid & 63;
    const int w = tid >> 6;
    const int frow = lane & 15;
    const int kg = lane >> 4;
    const int r0 = blockIdx.x * 128;

    f32x4 acc[4][2] = {};

    for (int kt = 0; kt < 512 / 64; ++kt) {
        #pragma unroll
        for (int i = 0; i < 4; ++i) {
            int flat = i * 256 + tid;
            int row = flat >> 3;
            int slot = flat & 7;
            int chunk = slot ^ (row & 7);
            gload16(&X[(size_t)(r0 + row) * 512 + kt * 64 + chunk * 8], &Xa[flat * 8]);
        }
        #pragma unroll
        for (int i = 0; i < 2; ++i) {
            int flat = i * 256 + tid;
            int row = flat >> 3;
            int slot = flat & 7;
            int chunk = slot ^ (row & 7);
            gload16(&W[(size_t)row * 512 + kt * 64 + chunk * 8], &Wa[flat * 8]);
        }
        __syncthreads();

        #pragma unroll
        for (int ks = 0; ks < 2; ++ks) {
            short8 af[4], bfr[2];
            #pragma unroll
            for (int m = 0; m < 4; ++m) {
                int row = m * 16 + frow;
                int phys = (ks * 4 + kg) ^ (row & 7);
                af[m] = *(const short8*)&Wa[row * 64 + phys * 8];
            }
            #pragma unroll
            for (int n = 0; n < 2; ++n) {
                int row = w * 32 + n * 16 + frow;
                int phys = (ks * 4 + kg) ^ (row & 7);
                bfr[n] = *(const short8*)&Xa[row * 64 + phys * 8];
            }
            #pragma unroll
            for (int m = 0; m < 4; ++m)
                #pragma unroll
                for (int n = 0; n < 2; ++n)
                    acc[m][n] = __builtin_amdgcn_mfma_f32_16x16x32_bf16(af[m], bfr[n], acc[m][n], 0, 0, 0);
        }
        __syncthreads();
    }

    #pragma unroll
    for (int m = 0; m < 4; ++m) {
        #pragma unroll
        for (int n = 0; n < 2; ++n) {
            int r = r0 + w * 32 + n * 16 + frow;
            int b = r >> 12;
            int l = r & (LL - 1);
            int e = m * 16 + kg * 4;
            #pragma unroll
            for (int i = 0; i < 4; ++i)
                out[((size_t)b * NCH + e + i) * LL + l] = acc[m][n][i];
        }
    }
}

// ---------------- conv1d (width 4, taps l-1..l+2) + silu, bf16 in/out ----------------
__global__ void conv_silu(const unsigned short* __restrict__ xzb,
                          const float* __restrict__ wx, const float* __restrict__ wz,
                          unsigned short* __restrict__ xqb, unsigned short* __restrict__ ycb) {
    __shared__ float s[67][64];
    const int b = blockIdx.z;
    const int l0 = blockIdx.x * 64;
    const int c0 = blockIdx.y * 64;
    const int tid = threadIdx.x;
    for (int idx = tid; idx < 67 * 16; idx += 256) {
        int rr = idx >> 4, u = idx & 15;
        int l = l0 - 1 + rr;
        float4 f;
        if (l >= 0 && l < LL) {
            ushort4 v = *(const ushort4*)&xzb[((size_t)b * LL + l) * DINNER + c0 + u * 4];
            f = make_float4(bf2f(v.x), bf2f(v.y), bf2f(v.z), bf2f(v.w));
        } else f = make_float4(0.f, 0.f, 0.f, 0.f);
        *(float4*)&s[rr][u * 4] = f;
    }
    __syncthreads();
    const int ct = (tid & 15) * 4;       // 4 consecutive channels
    const int c = c0 + ct;
    const bool isx = (c < DHALF);
    const float* wp = isx ? &wx[c * 4] : &wz[(c - DHALF) * 4];
    float4 w0 = *(const float4*)&wp[0];
    float4 w1 = *(const float4*)&wp[4];
    float4 w2 = *(const float4*)&wp[8];
    float4 w3 = *(const float4*)&wp[12];
    #pragma unroll
    for (int rep = 0; rep < 4; ++rep) {
        int ll = (tid >> 4) + rep * 16;
        float4 t0 = *(const float4*)&s[ll][ct];
        float4 t1 = *(const float4*)&s[ll + 1][ct];
        float4 t2 = *(const float4*)&s[ll + 2][ct];
        float4 t3 = *(const float4*)&s[ll + 3][ct];
        float v0 = w0.x*t0.x + w0.y*t1.x + w0.z*t2.x + w0.w*t3.x;
        float v1 = w1.x*t0.y + w1.y*t1.y + w1.z*t2.y + w1.w*t3.y;
        float v2 = w2.x*t0.z + w2.y*t1.z + w2.z*t2.z + w2.w*t3.z;
        float v3 = w3.x*t0.w + w3.y*t1.w + w3.z*t2.w + w3.w*t3.w;
        ushort4 o = make_ushort4(f2bf(silu_f(v0)), f2bf(silu_f(v1)),
                                 f2bf(silu_f(v2)), f2bf(silu_f(v3)));
        int l = l0 + ll;
        if (isx) *(ushort4*)&xqb[((size_t)b * LL + l) * DHALF + c] = o;
        else     *(ushort4*)&ycb[((size_t)b * LL + l) * DINNER + c] = o;
    }
}

// ---------------- single-pass fused scan (decoupled look-back) ----------------
// One block per (chunk c, d-half dg, batch b). Computes dt-GEMM + local scan, publishes
// aggregate (flag 1), looks back to resolve carry, publishes inclusive prefix (flag 2,
// separate buffer -> no overwrite race), then replays recurrence with carry and emits y.
// Deadlock-free: predecessors have smaller linear block ids (in-order HW dispatch).
__global__ __launch_bounds__(256, 4) void scan_fused(const unsigned short* __restrict__ xqb,
                      const float* __restrict__ xdbl, const float* __restrict__ Arow2T,
                      const float* __restrict__ dtw, const float* __restrict__ dtb,
                      const float* __restrict__ Dp,
                      float* __restrict__ sagg, float* __restrict__ hagg,
                      float* __restrict__ hpre, int* __restrict__ flags,
                      unsigned short* __restrict__ ycb) {
    __shared__ float s[64][CLEN];
    __shared__ int sflag;
    const int c = blockIdx.x;
    const int dg = blockIdx.y;
    const int b = blockIdx.z;
    const int tid = threadIdx.x;
    const int d = dg * 256 + tid;
    const int fbase = (b * 2 + dg) * NC;

    for (int idx = tid; idx < 64 * CLEN; idx += 256) {
        int ch = idx >> 4, ll = idx & (CLEN - 1);
        s[ch][ll] = xdbl[((size_t)b * NCH + ch) * LL + c * CLEN + ll];
    }
    float dtwreg[RK];
    #pragma unroll
    for (int r = 0; r < RK; r += 4) {
        float4 v = *(const float4*)&dtw[d * RK + r];
        dtwreg[r] = v.x; dtwreg[r+1] = v.y; dtwreg[r+2] = v.z; dtwreg[r+3] = v.w;
    }
    float Arow2[DSTATE];
    #pragma unroll
    for (int n = 0; n < DSTATE; ++n) Arow2[n] = Arow2T[n * DHALF + d];
    const float bias = dtb[d];
    float del[CLEN];
    #pragma unroll
    for (int t = 0; t < CLEN; ++t) del[t] = bias;
    __syncthreads();
    #pragma unroll
    for (int r = 0; r < RK; ++r) {
        float wv = dtwreg[r];
        #pragma unroll
        for (int q = 0; q < CLEN / 4; ++q) {
            float4 v = *(const float4*)&s[r][q * 4];
            del[q*4+0] = fmaf(v.x, wv, del[q*4+0]);
            del[q*4+1] = fmaf(v.y, wv, del[q*4+1]);
            del[q*4+2] = fmaf(v.z, wv, del[q*4+2]);
            del[q*4+3] = fmaf(v.w, wv, del[q*4+3]);
        }
    }
    float sdel = 0.f;
    #pragma unroll
    for (int t = 0; t < CLEN; ++t) { del[t] = softplus_f(del[t]); sdel += del[t]; }

    // local scan; keep x in registers for the replay
    float xv[CLEN];
    float h[DSTATE];
    #pragma unroll
    for (int n = 0; n < DSTATE; ++n) h[n] = 0.f;
    #pragma unroll
    for (int t = 0; t < CLEN; ++t) {
        xv[t] = bf2f(xqb[((size_t)b * LL + c * CLEN + t) * DHALF + d]);
        float dl = del[t];
        float dx = dl * xv[t];
        #pragma unroll
        for (int n = 0; n < DSTATE; ++n) {
            float dA = exp2_raw(dl * Arow2[n]);
            h[n] = fmaf(dA, h[n], dx * s[32 + n][t]);
        }
    }

    const size_t abase = (((size_t)b * NC + c) * DSTATE) * DHALF + d;
    float Hin[DSTATE];
    #pragma unroll
    for (int n = 0; n < DSTATE; ++n) Hin[n] = 0.f;

    if (c == 0) {
        // inclusive prefix == local aggregate
        #pragma unroll
        for (int n = 0; n < DSTATE; ++n) hpre[abase + (size_t)n * DHALF] = h[n];
        __threadfence();
        __syncthreads();
        if (tid == 0) atomicExch(&flags[fbase + 0], 2);
    } else {
        sagg[((size_t)b * NC + c) * DHALF + d] = sdel;
        #pragma unroll
        for (int n = 0; n < DSTATE; ++n) hagg[abase + (size_t)n * DHALF] = h[n];
        __threadfence();
        __syncthreads();
        if (tid == 0) atomicExch(&flags[fbase + c], 1);

        // look-back
        float S = 0.f;
        for (int j = c - 1; j >= 0; --j) {
            if (tid == 0) {
                int f;
                do { f = atomicAdd(&flags[fbase + j], 0);
                     if (f == 0) __builtin_amdgcn_s_sleep(1);
                } while (f == 0);
                sflag = f;
            }
            __syncthreads();
            int f = sflag;
            __threadfence();
            const float* hsrc = (f == 2) ? hpre : hagg;
            size_t jbase = (((size_t)b * NC + j) * DSTATE) * DHALF + d;
            #pragma unroll
            for (int n = 0; n < DSTATE; ++n)
                Hin[n] = fmaf(exp2_raw(Arow2[n] * S), hsrc[jbase + (size_t)n * DHALF], Hin[n]);
            if (f == 2) break;
            S += sagg[((size_t)b * NC + j) * DHALF + d];
            __syncthreads();   // protect sflag reuse
        }

        // publish inclusive prefix
        #pragma unroll
        for (int n = 0; n < DSTATE; ++n)
            hpre[abase + (size_t)n * DHALF] = fmaf(exp2_raw(Arow2[n] * sdel), Hin[n], h[n]);
        __threadfence();
        __syncthreads();
        if (tid == 0) atomicExch(&flags[fbase + c], 2);
    }

    // replay with carry, emit y
    #pragma unroll
    for (int n = 0; n < DSTATE; ++n) h[n] = Hin[n];
    const float Dv = Dp[d];
    #pragma unroll
    for (int t = 0; t < CLEN; ++t) {
        float dl = del[t];
        float dx = dl * xv[t];
        float y = Dv * xv[t];
        #pragma unroll
        for (int n = 0; n < DSTATE; ++n) {
            float dA = exp2_raw(dl * Arow2[n]);
            h[n] = fmaf(dA, h[n], dx * s[32 + n][t]);     // B rows
            y = fmaf(h[n], s[48 + n][t], y);              // C rows
        }
        ycb[((size_t)b * LL + c * CLEN + t) * DINNER + d] = f2bf(y);
    }
}

extern "C" void kernel_launch(void* const* d_in, const int* in_sizes, int n_in,
                              void* d_out, int out_size, void* d_ws, size_t ws_size,
                              hipStream_t stream) {
    const float* hidden     = (const float*)d_in[0];
    const float* in_proj_w  = (const float*)d_in[1];
    const float* conv_x_w   = (const float*)d_in[2];
    const float* conv_z_w   = (const float*)d_in[3];
    const float* x_proj_w   = (const float*)d_in[4];
    const float* dt_proj_w  = (const float*)d_in[5];
    const float* dt_proj_b  = (const float*)d_in[6];
    const float* A_log      = (const float*)d_in[7];
    const float* Dp         = (const float*)d_in[8];
    const float* out_proj_w = (const float*)d_in[9];
    float* out = (float*)d_out;

    float* ws_f = (float*)d_ws;
    // float-unit offsets (sizes in floats)
    unsigned short* Wb  = (unsigned short*)(ws_f + 0);         // 262,144 f
    unsigned short* Wob = (unsigned short*)(ws_f + 262144);    // 262,144 f
    unsigned short* Wxb = (unsigned short*)(ws_f + 524288);    // 16,384 f
    unsigned short* Hb  = (unsigned short*)(ws_f + 540672);    // 2,097,152 f [cast->K1; then sagg]
    unsigned short* xzb = (unsigned short*)(ws_f + 2637824);   // 4,194,304 f [K1->conv; then hagg]
    unsigned short* xqb = (unsigned short*)(ws_f + 6832128);   // 2,097,152 f bf16 (b,l,512)
    unsigned short* ycb = (unsigned short*)(ws_f + 8929280);   // 4,194,304 f bf16 (b,l,1024)
    float* xdbl   = ws_f + 13123584;                           // 524,288 f (b,64,l)
    float* Arow2T = ws_f + 13647872;                           // 8,192 f [16][512]
    float* hpre   = ws_f + 13656064;                           // 4,194,304 f
    int*   flags  = (int*)(ws_f + 17850368);                   // 1,024 ints (end ~71.4 MB)
    // aliases (dead regions at scan time):
    float* sagg = ws_f + 540672;                               // 262,144 f (over Hb)
    float* hagg = ws_f + 2637824;                              // 4,194,304 f (over xzb)

    dim3 blk(256);

    // flags must be zero before scan_fused (stream-ordered, graph-capturable)
    hipMemsetAsync(flags, 0, BB * 2 * NC * sizeof(int), stream);

    // K0: casts + Arow2T precompute
    cast_all<<<dim3((H4 + W14 + W24 + W34 + NA + 255) / 256), blk, 0, stream>>>(
        hidden, in_proj_w, out_proj_w, x_proj_w, A_log, Hb, Wb, Wob, Wxb, Arow2T);
    // K1: in_proj (bf16 MFMA) -> xzb bf16 (b,l,1024)   [grid 64x16]
    gemm_mfma<DMODEL, DINNER, true><<<dim3(BB * LL / 128, DINNER / 64), blk, 0, stream>>>(Wb, Hb, xzb);
    // K2: conv + silu -> xqb bf16; z-half -> ycb cols 512..1023
    conv_silu<<<dim3(LL / 64, DINNER / 64, BB), blk, 0, stream>>>(xzb, conv_x_w, conv_z_w, xqb, ycb);
    // K3: x_proj (bf16 MFMA) -> xdbl (b,64,l) fp32
    gemm_xproj<<<dim3(BB * LL / 128), blk, 0, stream>>>(Wxb, xqb, xdbl);
    // K4: single-pass fused scan -> ycb bf16 cols 0..511  [Hb dead -> sagg; xzb dead -> hagg]
    scan_fused<<<dim3(NC, 2, BB), blk, 0, stream>>>(xqb, xdbl, Arow2T, dt_proj_w, dt_proj_b,
                                                    Dp, sagg, hagg, hpre, flags, ycb);
    // K5: out_proj (bf16 MFMA) -> out (b,l,512) fp32   [grid 64x8]
    gemm_mfma<DINNER, DMODEL, false><<<dim3(BB * LL / 128, DMODEL / 64), blk, 0, stream>>>(Wob, ycb, out);
}

// Round 16
// 127.689 us; speedup vs baseline: 20.8413x; 20.8413x over previous
//
#include <hip/hip_runtime.h>
#include <math.h>

#define BB 2
#define LL 4096
#define DMODEL 512
#define DINNER 1024
#define DHALF 512
#define DSTATE 16
#define RK 32
#define NCH 64          // x_dbl channels (32 dt + 16 B + 16 C)
#define NC 256          // scan chunks
#define CLEN (LL/NC)    // 16
#define NG 16           // chunk groups (for scan2)
#define GL (NC/NG)      // 16 chunks per group
#define LOG2E 1.44269504088896f

typedef __attribute__((ext_vector_type(8))) short short8;
typedef __attribute__((ext_vector_type(4))) float f32x4;

__device__ __forceinline__ float silu_f(float v) { return v / (1.f + __expf(-v)); }

// round-to-nearest-even fp32 -> bf16 (inputs finite)
__device__ __forceinline__ unsigned short f2bf(float x) {
    unsigned int u = __float_as_uint(x);
    u += 0x7fffu + ((u >> 16) & 1u);
    return (unsigned short)(u >> 16);
}
__device__ __forceinline__ float bf2f(unsigned short u) {
    return __uint_as_float((unsigned int)u << 16);
}

__device__ __forceinline__ float softplus_f(float x) {
    return fmaxf(x, 0.f) + __logf(1.f + __expf(-fabsf(x)));
}

// raw v_exp_f32 (base-2), no libm guards
__device__ __forceinline__ float exp2_raw(float x) { return __builtin_amdgcn_exp2f(x); }

__device__ __forceinline__ void gload16(const unsigned short* g, unsigned short* l) {
    __builtin_amdgcn_global_load_lds((const __attribute__((address_space(1))) void*)g,
                                     (__attribute__((address_space(3))) void*)l, 16, 0, 0);
}

// ---------------- cast kernel: fp32->bf16 for H/W1/W2/Wx, plus Arow2T precompute --------
#define H4  1048576   // hidden vec4 count
#define W14 131072    // in_proj
#define W24 131072    // out_proj
#define W34 8192      // x_proj
#define NA  8192      // Arow2T elements (16 x 512)
__global__ void cast_all(const float* __restrict__ hid, const float* __restrict__ w1,
                         const float* __restrict__ w2, const float* __restrict__ w3,
                         const float* __restrict__ A_log,
                         unsigned short* __restrict__ Hb, unsigned short* __restrict__ Wb,
                         unsigned short* __restrict__ Wob, unsigned short* __restrict__ Wxb,
                         float* __restrict__ Arow2T) {
    int i = blockIdx.x * 256 + threadIdx.x;
    if (i >= H4 + W14 + W24 + W34) {
        int j = i - (H4 + W14 + W24 + W34);
        if (j < NA) {
            int n = j >> 9, d = j & 511;
            Arow2T[j] = -expf(A_log[d * DSTATE + n]) * LOG2E;   // [n][d] layout
        }
        return;
    }
    const float* src; unsigned short* dst; int j;
    if (i < H4)                    { src = hid; dst = Hb;  j = i; }
    else if (i < H4 + W14)         { src = w1;  dst = Wb;  j = i - H4; }
    else if (i < H4 + W14 + W24)   { src = w2;  dst = Wob; j = i - H4 - W14; }
    else                           { src = w3;  dst = Wxb; j = i - H4 - W14 - W24; }
    float4 v = *(const float4*)&src[(size_t)j * 4];
    ushort4 o = make_ushort4(f2bf(v.x), f2bf(v.y), f2bf(v.z), f2bf(v.w));
    *(ushort4*)&dst[(size_t)j * 4] = o;
}

// ---------------- bf16 MFMA GEMM, 128r x 64e tile ----------------
// W: [E][K] bf16 k-major.  X: [R][K] bf16 k-major.  out[r][e] = sum_k W[e][k]*X[r][k]
template<int K, int E, bool BF16OUT>
__global__ __launch_bounds__(256, 4) void gemm_mfma(const unsigned short* __restrict__ W,
                                                    const unsigned short* __restrict__ X,
                                                    void* __restrict__ outv) {
    __shared__ unsigned short Xa[128 * 64];   // [row][k], 16B-chunk XOR-swizzled
    __shared__ unsigned short Wa[64 * 64];
    const int tid = threadIdx.x;
    const int lane = tid & 63;
    const int w = tid >> 6;
    const int frow = lane & 15;
    const int kg = lane >> 4;
    const int e0 = blockIdx.y * 64;
    const int r0 = blockIdx.x * 128;

    f32x4 acc[4][2] = {};

    for (int kt = 0; kt < K / 64; ++kt) {
        #pragma unroll
        for (int i = 0; i < 4; ++i) {
            int flat = i * 256 + tid;         // 16B units
            int row = flat >> 3;
            int slot = flat & 7;
            int chunk = slot ^ (row & 7);
            gload16(&X[(size_t)(r0 + row) * K + kt * 64 + chunk * 8], &Xa[flat * 8]);
        }
        #pragma unroll
        for (int i = 0; i < 2; ++i) {
            int flat = i * 256 + tid;         // 0..511
            int row = flat >> 3;              // 0..63
            int slot = flat & 7;
            int chunk = slot ^ (row & 7);
            gload16(&W[(size_t)(e0 + row) * K + kt * 64 + chunk * 8], &Wa[flat * 8]);
        }
        __syncthreads();

        #pragma unroll
        for (int ks = 0; ks < 2; ++ks) {
            short8 af[4], bfr[2];
            #pragma unroll
            for (int m = 0; m < 4; ++m) {
                int row = m * 16 + frow;
                int phys = (ks * 4 + kg) ^ (row & 7);
                af[m] = *(const short8*)&Wa[row * 64 + phys * 8];
            }
            #pragma unroll
            for (int n = 0; n < 2; ++n) {
                int row = w * 32 + n * 16 + frow;
                int phys = (ks * 4 + kg) ^ (row & 7);
                bfr[n] = *(const short8*)&Xa[row * 64 + phys * 8];
            }
            #pragma unroll
            for (int m = 0; m < 4; ++m)
                #pragma unroll
                for (int n = 0; n < 2; ++n)
                    acc[m][n] = __builtin_amdgcn_mfma_f32_16x16x32_bf16(af[m], bfr[n], acc[m][n], 0, 0, 0);
        }
        __syncthreads();
    }

    #pragma unroll
    for (int m = 0; m < 4; ++m) {
        #pragma unroll
        for (int n = 0; n < 2; ++n) {
            int e = e0 + m * 16 + kg * 4;
            int r = r0 + w * 32 + n * 16 + frow;
            f32x4 a = acc[m][n];
            if constexpr (BF16OUT) {
                ushort4 o = make_ushort4(f2bf(a.x), f2bf(a.y), f2bf(a.z), f2bf(a.w));
                *(ushort4*)&((unsigned short*)outv)[(size_t)r * E + e] = o;
            } else {
                *(f32x4*)&((float*)outv)[(size_t)r * E + e] = a;
            }
        }
    }
}

// ---------------- x_proj MFMA: 128r x 64e tile, out (b, ch, l) fp32 ----------------
__global__ __launch_bounds__(256) void gemm_xproj(const unsigned short* __restrict__ W,
                                                  const unsigned short* __restrict__ X,
                                                  float* __restrict__ out) {
    __shared__ unsigned short Xa[128 * 64];
    __shared__ unsigned short Wa[64 * 64];
    const int tid = threadIdx.x;
    const int lane = tid & 63;
    const int w = tid >> 6;
    const int frow = lane & 15;
    const int kg = lane >> 4;
    const int r0 = blockIdx.x * 128;

    f32x4 acc[4][2] = {};

    for (int kt = 0; kt < 512 / 64; ++kt) {
        #pragma unroll
        for (int i = 0; i < 4; ++i) {
            int flat = i * 256 + tid;
            int row = flat >> 3;
            int slot = flat & 7;
            int chunk = slot ^ (row & 7);
            gload16(&X[(size_t)(r0 + row) * 512 + kt * 64 + chunk * 8], &Xa[flat * 8]);
        }
        #pragma unroll
        for (int i = 0; i < 2; ++i) {
            int flat = i * 256 + tid;
            int row = flat >> 3;
            int slot = flat & 7;
            int chunk = slot ^ (row & 7);
            gload16(&W[(size_t)row * 512 + kt * 64 + chunk * 8], &Wa[flat * 8]);
        }
        __syncthreads();

        #pragma unroll
        for (int ks = 0; ks < 2; ++ks) {
            short8 af[4], bfr[2];
            #pragma unroll
            for (int m = 0; m < 4; ++m) {
                int row = m * 16 + frow;
                int phys = (ks * 4 + kg) ^ (row & 7);
                af[m] = *(const short8*)&Wa[row * 64 + phys * 8];
            }
            #pragma unroll
            for (int n = 0; n < 2; ++n) {
                int row = w * 32 + n * 16 + frow;
                int phys = (ks * 4 + kg) ^ (row & 7);
                bfr[n] = *(const short8*)&Xa[row * 64 + phys * 8];
            }
            #pragma unroll
            for (int m = 0; m < 4; ++m)
                #pragma unroll
                for (int n = 0; n < 2; ++n)
                    acc[m][n] = __builtin_amdgcn_mfma_f32_16x16x32_bf16(af[m], bfr[n], acc[m][n], 0, 0, 0);
        }
        __syncthreads();
    }

    #pragma unroll
    for (int m = 0; m < 4; ++m) {
        #pragma unroll
        for (int n = 0; n < 2; ++n) {
            int r = r0 + w * 32 + n * 16 + frow;
            int b = r >> 12;
            int l = r & (LL - 1);
            int e = m * 16 + kg * 4;
            #pragma unroll
            for (int i = 0; i < 4; ++i)
                out[((size_t)b * NCH + e + i) * LL + l] = acc[m][n][i];
        }
    }
}

// ---------------- conv1d (width 4, taps l-1..l+2) + silu, bf16 in/out ----------------
__global__ void conv_silu(const unsigned short* __restrict__ xzb,
                          const float* __restrict__ wx, const float* __restrict__ wz,
                          unsigned short* __restrict__ xqb, unsigned short* __restrict__ ycb) {
    __shared__ float s[67][64];
    const int b = blockIdx.z;
    const int l0 = blockIdx.x * 64;
    const int c0 = blockIdx.y * 64;
    const int tid = threadIdx.x;
    for (int idx = tid; idx < 67 * 16; idx += 256) {
        int rr = idx >> 4, u = idx & 15;
        int l = l0 - 1 + rr;
        float4 f;
        if (l >= 0 && l < LL) {
            ushort4 v = *(const ushort4*)&xzb[((size_t)b * LL + l) * DINNER + c0 + u * 4];
            f = make_float4(bf2f(v.x), bf2f(v.y), bf2f(v.z), bf2f(v.w));
        } else f = make_float4(0.f, 0.f, 0.f, 0.f);
        *(float4*)&s[rr][u * 4] = f;
    }
    __syncthreads();
    const int ct = (tid & 15) * 4;       // 4 consecutive channels
    const int c = c0 + ct;
    const bool isx = (c < DHALF);
    const float* wp = isx ? &wx[c * 4] : &wz[(c - DHALF) * 4];
    float4 w0 = *(const float4*)&wp[0];
    float4 w1 = *(const float4*)&wp[4];
    float4 w2 = *(const float4*)&wp[8];
    float4 w3 = *(const float4*)&wp[12];
    #pragma unroll
    for (int rep = 0; rep < 4; ++rep) {
        int ll = (tid >> 4) + rep * 16;
        float4 t0 = *(const float4*)&s[ll][ct];
        float4 t1 = *(const float4*)&s[ll + 1][ct];
        float4 t2 = *(const float4*)&s[ll + 2][ct];
        float4 t3 = *(const float4*)&s[ll + 3][ct];
        float v0 = w0.x*t0.x + w0.y*t1.x + w0.z*t2.x + w0.w*t3.x;
        float v1 = w1.x*t0.y + w1.y*t1.y + w1.z*t2.y + w1.w*t3.y;
        float v2 = w2.x*t0.z + w2.y*t1.z + w2.z*t2.z + w2.w*t3.z;
        float v3 = w3.x*t0.w + w3.y*t1.w + w3.z*t2.w + w3.w*t3.w;
        ushort4 o = make_ushort4(f2bf(silu_f(v0)), f2bf(silu_f(v1)),
                                 f2bf(silu_f(v2)), f2bf(silu_f(v3)));
        int l = l0 + ll;
        if (isx) *(ushort4*)&xqb[((size_t)b * LL + l) * DHALF + c] = o;
        else     *(ushort4*)&ycb[((size_t)b * LL + l) * DINNER + c] = o;
    }
}

// ---------------- scan pass 1: fused dt + chunk-local scan -> (sdel, del, h_end) -------
// xdbl (b, 64, l): ch 0..31 = dt_rank rows, 32..47 = B, 48..63 = C
__global__ __launch_bounds__(256, 4) void scan1(const unsigned short* __restrict__ xqb,
                      const float* __restrict__ xdbl, const float* __restrict__ Arow2T,
                      const float* __restrict__ dtw, const float* __restrict__ dtb,
                      float* __restrict__ sdelb, float* __restrict__ delb,
                      float* __restrict__ hend) {
    __shared__ float s[48][CLEN];
    const int b = blockIdx.z;
    const int d = blockIdx.y * 256 + threadIdx.x;
    const int c = blockIdx.x;
    const int tid = threadIdx.x;
    for (int idx = tid; idx < 48 * CLEN; idx += 256) {
        int ch = idx >> 4, ll = idx & (CLEN - 1);
        s[ch][ll] = xdbl[((size_t)b * NCH + ch) * LL + c * CLEN + ll];
    }
    float dtwreg[RK];
    #pragma unroll
    for (int r = 0; r < RK; r += 4) {
        float4 v = *(const float4*)&dtw[d * RK + r];
        dtwreg[r] = v.x; dtwreg[r+1] = v.y; dtwreg[r+2] = v.z; dtwreg[r+3] = v.w;
    }
    float Arow2[DSTATE];
    #pragma unroll
    for (int n = 0; n < DSTATE; ++n) Arow2[n] = Arow2T[n * DHALF + d];   // coalesced
    const float bias = dtb[d];
    float del[CLEN];
    #pragma unroll
    for (int t = 0; t < CLEN; ++t) del[t] = bias;
    __syncthreads();
    #pragma unroll
    for (int r = 0; r < RK; ++r) {
        float wv = dtwreg[r];
        #pragma unroll
        for (int q = 0; q < CLEN / 4; ++q) {
            float4 v = *(const float4*)&s[r][q * 4];
            del[q*4+0] = fmaf(v.x, wv, del[q*4+0]);
            del[q*4+1] = fmaf(v.y, wv, del[q*4+1]);
            del[q*4+2] = fmaf(v.z, wv, del[q*4+2]);
            del[q*4+3] = fmaf(v.w, wv, del[q*4+3]);
        }
    }
    float sdel = 0.f;
    #pragma unroll
    for (int t = 0; t < CLEN; ++t) { del[t] = softplus_f(del[t]); sdel += del[t]; }
    size_t dbase = ((size_t)b * LL + c * CLEN) * DHALF + d;
    #pragma unroll
    for (int t = 0; t < CLEN; ++t) delb[dbase + (size_t)t * DHALF] = del[t];

    float h[DSTATE];
    #pragma unroll
    for (int n = 0; n < DSTATE; ++n) h[n] = 0.f;
    #pragma unroll
    for (int t = 0; t < CLEN; ++t) {
        float dl = del[t];
        float xv = bf2f(xqb[((size_t)b * LL + c * CLEN + t) * DHALF + d]);
        float dx = dl * xv;
        #pragma unroll
        for (int n = 0; n < DSTATE; ++n) {
            float dA = exp2_raw(dl * Arow2[n]);
            h[n] = fmaf(dA, h[n], dx * s[32 + n][t]);
        }
    }
    sdelb[((size_t)b * NC + c) * DHALF + d] = sdel;
    size_t base = (((size_t)b * NC + c) * DSTATE) * DHALF + d;
    #pragma unroll
    for (int n = 0; n < DSTATE; ++n)
        hend[base + (size_t)n * DHALF] = h[n];
}

// ---------------- scan2a: within-group prefix (hend in place) + group totals -----------
__global__ void scan2a(const float* __restrict__ sdelb, float* __restrict__ hend,
                       const float* __restrict__ Arow2T,
                       float* __restrict__ gP, float* __restrict__ gH) {
    int flat = blockIdx.x * 256 + threadIdx.x;   // B*NG*DSTATE*DHALF = 262144
    int d = flat & (DHALF - 1);
    int n = (flat >> 9) & (DSTATE - 1);
    int g = (flat >> 13) & (NG - 1);
    int b = flat >> 17;
    const float Arow2 = Arow2T[n * DHALF + d];
    const size_t stride = (size_t)DSTATE * DHALF;
    size_t idx = (((size_t)b * NC + g * GL) * DSTATE + n) * DHALF + d;
    size_t sidx = ((size_t)b * NC + g * GL) * DHALF + d;
    float S = 0.f, H = 0.f;
    #pragma unroll
    for (int j = 0; j < GL; ++j) {
        float sd = sdelb[sidx + (size_t)j * DHALF];
        float h = hend[idx];
        hend[idx] = H;            // store within-group carry-in
        H = fmaf(exp2_raw(Arow2 * sd), H, h);
        S += sd;
        idx += stride;
    }
    size_t gi = (((size_t)b * NG + g) * DSTATE + n) * DHALF + d;
    gP[gi] = exp2_raw(Arow2 * S);
    gH[gi] = H;
}

// ---------------- scan pass 3: load del, group-carry in-kernel, emit y -> ycb ----------
__global__ __launch_bounds__(256, 4) void scan3(const unsigned short* __restrict__ xqb,
                      const float* __restrict__ xdbl, const float* __restrict__ Arow2T,
                      const float* __restrict__ delb, const float* __restrict__ Dp,
                      const float* __restrict__ sdelb, const float* __restrict__ hend,
                      const float* __restrict__ gP, const float* __restrict__ gH,
                      unsigned short* __restrict__ ycb) {
    __shared__ float s[32][CLEN];       // B rows + C rows only
    const int b = blockIdx.z;
    const int d = blockIdx.y * 256 + threadIdx.x;
    const int c = blockIdx.x;
    const int tid = threadIdx.x;
    const int g = c / GL;
    for (int idx = tid; idx < 32 * CLEN; idx += 256) {
        int ch = 32 + (idx >> 4), ll = idx & (CLEN - 1);
        s[idx >> 4][ll] = xdbl[((size_t)b * NCH + ch) * LL + c * CLEN + ll];
    }
    float Arow2[DSTATE];
    #pragma unroll
    for (int n = 0; n < DSTATE; ++n) Arow2[n] = Arow2T[n * DHALF + d];

    // group carry: serial scan over groups 0..g-1 (uniform per block, coalesced loads)
    float Hcar[DSTATE];
    #pragma unroll
    for (int n = 0; n < DSTATE; ++n) Hcar[n] = 0.f;
    for (int gp = 0; gp < g; ++gp) {
        size_t gi = (((size_t)b * NG + gp) * DSTATE) * DHALF + d;
        #pragma unroll
        for (int n = 0; n < DSTATE; ++n)
            Hcar[n] = fmaf(gP[gi + (size_t)n * DHALF], Hcar[n], gH[gi + (size_t)n * DHALF]);
    }
    float Sc = 0.f;
    for (int j = g * GL; j < c; ++j)
        Sc += sdelb[((size_t)b * NC + j) * DHALF + d];

    float h[DSTATE];
    size_t base = (((size_t)b * NC + c) * DSTATE) * DHALF + d;
    #pragma unroll
    for (int n = 0; n < DSTATE; ++n)
        h[n] = fmaf(exp2_raw(Arow2[n] * Sc), Hcar[n], hend[base + (size_t)n * DHALF]);

    float del[CLEN];
    size_t dbase = ((size_t)b * LL + c * CLEN) * DHALF + d;
    #pragma unroll
    for (int t = 0; t < CLEN; ++t) del[t] = delb[dbase + (size_t)t * DHALF];

    const float Dv = Dp[d];
    __syncthreads();
    #pragma unroll
    for (int t = 0; t < CLEN; ++t) {
        float dl = del[t];
        float xv = bf2f(xqb[((size_t)b * LL + c * CLEN + t) * DHALF + d]);
        float dx = dl * xv;
        float y = Dv * xv;
        #pragma unroll
        for (int n = 0; n < DSTATE; ++n) {
            float dA = exp2_raw(dl * Arow2[n]);
            h[n] = fmaf(dA, h[n], dx * s[n][t]);          // B rows
            y = fmaf(h[n], s[16 + n][t], y);              // C rows
        }
        ycb[((size_t)b * LL + c * CLEN + t) * DINNER + d] = f2bf(y);
    }
}

extern "C" void kernel_launch(void* const* d_in, const int* in_sizes, int n_in,
                              void* d_out, int out_size, void* d_ws, size_t ws_size,
                              hipStream_t stream) {
    const float* hidden     = (const float*)d_in[0];
    const float* in_proj_w  = (const float*)d_in[1];
    const float* conv_x_w   = (const float*)d_in[2];
    const float* conv_z_w   = (const float*)d_in[3];
    const float* x_proj_w   = (const float*)d_in[4];
    const float* dt_proj_w  = (const float*)d_in[5];
    const float* dt_proj_b  = (const float*)d_in[6];
    const float* A_log      = (const float*)d_in[7];
    const float* Dp         = (const float*)d_in[8];
    const float* out_proj_w = (const float*)d_in[9];
    float* out = (float*)d_out;

    float* ws_f = (float*)d_ws;
    // float-unit offsets (sizes in floats)
    unsigned short* Wb  = (unsigned short*)(ws_f + 0);         // 262,144 f
    unsigned short* Wob = (unsigned short*)(ws_f + 262144);    // 262,144 f
    unsigned short* Wxb = (unsigned short*)(ws_f + 524288);    // 16,384 f
    unsigned short* Hb  = (unsigned short*)(ws_f + 540672);    // 2,097,152 f [cast->K1; then sdel]
    unsigned short* xzb = (unsigned short*)(ws_f + 2637824);   // 4,194,304 f [K1->conv; then hend]
    unsigned short* xqb = (unsigned short*)(ws_f + 6832128);   // 2,097,152 f bf16 (b,l,512)
    unsigned short* ycb = (unsigned short*)(ws_f + 8929280);   // 4,194,304 f bf16 (b,l,1024)
    float* xdbl   = ws_f + 13123584;                           // 524,288 f (b,64,l)
    float* gP     = ws_f + 13647872;                           // 262,144 f
    float* gH     = ws_f + 13910016;                           // 262,144 f
    float* Arow2T = ws_f + 14172160;                           // 8,192 f [16][512]
    float* delb   = ws_f + 14180352;                           // 4,194,304 f (B*L*DHALF)
    // aliases (dead regions at scan time):
    float* sdel = ws_f + 540672;                               // 262,144 f (over Hb)
    float* hend = ws_f + 2637824;                              // 4,194,304 f (over xzb)

    dim3 blk(256);

    // K0: casts + Arow2T precompute
    cast_all<<<dim3((H4 + W14 + W24 + W34 + NA + 255) / 256), blk, 0, stream>>>(
        hidden, in_proj_w, out_proj_w, x_proj_w, A_log, Hb, Wb, Wob, Wxb, Arow2T);
    // K1: in_proj (bf16 MFMA) -> xzb bf16 (b,l,1024)   [grid 64x16 = 1024 blocks]
    gemm_mfma<DMODEL, DINNER, true><<<dim3(BB * LL / 128, DINNER / 64), blk, 0, stream>>>(Wb, Hb, xzb);
    // K2: conv + silu -> xqb bf16; z-half -> ycb cols 512..1023
    conv_silu<<<dim3(LL / 64, DINNER / 64, BB), blk, 0, stream>>>(xzb, conv_x_w, conv_z_w, xqb, ycb);
    // K3: x_proj (bf16 MFMA) -> xdbl (b,64,l) fp32
    gemm_xproj<<<dim3(BB * LL / 128), blk, 0, stream>>>(Wxb, xqb, xdbl);
    // K5: fused dt + chunk-local scan  [Hb dead -> sdel; xzb dead -> hend]
    scan1<<<dim3(NC, DHALF / 256, BB), blk, 0, stream>>>(xqb, xdbl, Arow2T, dt_proj_w, dt_proj_b,
                                                         sdel, delb, hend);
    // K5b: within-group combine; group totals in gP/gH
    scan2a<<<dim3(BB * NG * DSTATE * DHALF / 256), blk, 0, stream>>>(sdel, hend, Arow2T, gP, gH);
    // K6: scan3 does group-carry + recompute with carry -> ycb bf16 cols 0..511
    scan3<<<dim3(NC, DHALF / 256, BB), blk, 0, stream>>>(xqb, xdbl, Arow2T, delb, Dp,
                                                         sdel, hend, gP, gH, ycb);
    // K7: out_proj (bf16 MFMA) -> out (b,l,512) fp32   [grid 64x8 = 512 blocks]
    gemm_mfma<DINNER, DMODEL, false><<<dim3(BB * LL / 128, DMODEL / 64), blk, 0, stream>>>(Wob, ycb, out);
}

// Round 17
// 127.041 us; speedup vs baseline: 20.9476x; 1.0051x over previous
//
#include <hip/hip_runtime.h>
#include <math.h>

#define BB 2
#define LL 4096
#define DMODEL 512
#define DINNER 1024
#define DHALF 512
#define DSTATE 16
#define RK 32
#define NCH 64          // x_dbl channels (32 dt + 16 B + 16 C)
#define NC 256          // scan chunks
#define CLEN (LL/NC)    // 16
#define NG 16           // chunk groups (for scan2)
#define GL (NC/NG)      // 16 chunks per group
#define LOG2E 1.44269504088896f

typedef __attribute__((ext_vector_type(8))) short short8;
typedef __attribute__((ext_vector_type(4))) float f32x4;

__device__ __forceinline__ float silu_f(float v) { return v / (1.f + __expf(-v)); }

// round-to-nearest-even fp32 -> bf16 (inputs finite)
__device__ __forceinline__ unsigned short f2bf(float x) {
    unsigned int u = __float_as_uint(x);
    u += 0x7fffu + ((u >> 16) & 1u);
    return (unsigned short)(u >> 16);
}
__device__ __forceinline__ float bf2f(unsigned short u) {
    return __uint_as_float((unsigned int)u << 16);
}

__device__ __forceinline__ float softplus_f(float x) {
    return fmaxf(x, 0.f) + __logf(1.f + __expf(-fabsf(x)));
}

// raw v_exp_f32 (base-2), no libm guards
__device__ __forceinline__ float exp2_raw(float x) { return __builtin_amdgcn_exp2f(x); }

__device__ __forceinline__ void gload16(const unsigned short* g, unsigned short* l) {
    __builtin_amdgcn_global_load_lds((const __attribute__((address_space(1))) void*)g,
                                     (__attribute__((address_space(3))) void*)l, 16, 0, 0);
}

// ---------------- cast kernel: fp32->bf16 for H/W1/W2/Wx, plus Arow2T precompute --------
#define H4  1048576   // hidden vec4 count
#define W14 131072    // in_proj
#define W24 131072    // out_proj
#define W34 8192      // x_proj
#define NA  8192      // Arow2T elements (16 x 512)
__global__ void cast_all(const float* __restrict__ hid, const float* __restrict__ w1,
                         const float* __restrict__ w2, const float* __restrict__ w3,
                         const float* __restrict__ A_log,
                         unsigned short* __restrict__ Hb, unsigned short* __restrict__ Wb,
                         unsigned short* __restrict__ Wob, unsigned short* __restrict__ Wxb,
                         float* __restrict__ Arow2T) {
    int i = blockIdx.x * 256 + threadIdx.x;
    if (i >= H4 + W14 + W24 + W34) {
        int j = i - (H4 + W14 + W24 + W34);
        if (j < NA) {
            int n = j >> 9, d = j & 511;
            Arow2T[j] = -expf(A_log[d * DSTATE + n]) * LOG2E;   // [n][d] layout
        }
        return;
    }
    const float* src; unsigned short* dst; int j;
    if (i < H4)                    { src = hid; dst = Hb;  j = i; }
    else if (i < H4 + W14)         { src = w1;  dst = Wb;  j = i - H4; }
    else if (i < H4 + W14 + W24)   { src = w2;  dst = Wob; j = i - H4 - W14; }
    else                           { src = w3;  dst = Wxb; j = i - H4 - W14 - W24; }
    float4 v = *(const float4*)&src[(size_t)j * 4];
    ushort4 o = make_ushort4(f2bf(v.x), f2bf(v.y), f2bf(v.z), f2bf(v.w));
    *(ushort4*)&dst[(size_t)j * 4] = o;
}

// ---------------- bf16 MFMA GEMM, 128r x 64e tile ----------------
// W: [E][K] bf16 k-major.  X: [R][K] bf16 k-major.  out[r][e] = sum_k W[e][k]*X[r][k]
template<int K, int E, bool BF16OUT>
__global__ __launch_bounds__(256, 4) void gemm_mfma(const unsigned short* __restrict__ W,
                                                    const unsigned short* __restrict__ X,
                                                    void* __restrict__ outv) {
    __shared__ unsigned short Xa[128 * 64];   // [row][k], 16B-chunk XOR-swizzled
    __shared__ unsigned short Wa[64 * 64];
    const int tid = threadIdx.x;
    const int lane = tid & 63;
    const int w = tid >> 6;
    const int frow = lane & 15;
    const int kg = lane >> 4;
    const int e0 = blockIdx.y * 64;
    const int r0 = blockIdx.x * 128;

    f32x4 acc[4][2] = {};

    for (int kt = 0; kt < K / 64; ++kt) {
        #pragma unroll
        for (int i = 0; i < 4; ++i) {
            int flat = i * 256 + tid;         // 16B units
            int row = flat >> 3;
            int slot = flat & 7;
            int chunk = slot ^ (row & 7);
            gload16(&X[(size_t)(r0 + row) * K + kt * 64 + chunk * 8], &Xa[flat * 8]);
        }
        #pragma unroll
        for (int i = 0; i < 2; ++i) {
            int flat = i * 256 + tid;         // 0..511
            int row = flat >> 3;              // 0..63
            int slot = flat & 7;
            int chunk = slot ^ (row & 7);
            gload16(&W[(size_t)(e0 + row) * K + kt * 64 + chunk * 8], &Wa[flat * 8]);
        }
        __syncthreads();

        #pragma unroll
        for (int ks = 0; ks < 2; ++ks) {
            short8 af[4], bfr[2];
            #pragma unroll
            for (int m = 0; m < 4; ++m) {
                int row = m * 16 + frow;
                int phys = (ks * 4 + kg) ^ (row & 7);
                af[m] = *(const short8*)&Wa[row * 64 + phys * 8];
            }
            #pragma unroll
            for (int n = 0; n < 2; ++n) {
                int row = w * 32 + n * 16 + frow;
                int phys = (ks * 4 + kg) ^ (row & 7);
                bfr[n] = *(const short8*)&Xa[row * 64 + phys * 8];
            }
            #pragma unroll
            for (int m = 0; m < 4; ++m)
                #pragma unroll
                for (int n = 0; n < 2; ++n)
                    acc[m][n] = __builtin_amdgcn_mfma_f32_16x16x32_bf16(af[m], bfr[n], acc[m][n], 0, 0, 0);
        }
        __syncthreads();
    }

    #pragma unroll
    for (int m = 0; m < 4; ++m) {
        #pragma unroll
        for (int n = 0; n < 2; ++n) {
            int e = e0 + m * 16 + kg * 4;
            int r = r0 + w * 32 + n * 16 + frow;
            f32x4 a = acc[m][n];
            if constexpr (BF16OUT) {
                ushort4 o = make_ushort4(f2bf(a.x), f2bf(a.y), f2bf(a.z), f2bf(a.w));
                *(ushort4*)&((unsigned short*)outv)[(size_t)r * E + e] = o;
            } else {
                *(f32x4*)&((float*)outv)[(size_t)r * E + e] = a;
            }
        }
    }
}

// ---------------- x_proj MFMA: 128r x 64e tile, out (b, ch, l) fp32 ----------------
__global__ __launch_bounds__(256) void gemm_xproj(const unsigned short* __restrict__ W,
                                                  const unsigned short* __restrict__ X,
                                                  float* __restrict__ out) {
    __shared__ unsigned short Xa[128 * 64];
    __shared__ unsigned short Wa[64 * 64];
    const int tid = threadIdx.x;
    const int lane = tid & 63;
    const int w = tid >> 6;
    const int frow = lane & 15;
    const int kg = lane >> 4;
    const int r0 = blockIdx.x * 128;

    f32x4 acc[4][2] = {};

    for (int kt = 0; kt < 512 / 64; ++kt) {
        #pragma unroll
        for (int i = 0; i < 4; ++i) {
            int flat = i * 256 + tid;
            int row = flat >> 3;
            int slot = flat & 7;
            int chunk = slot ^ (row & 7);
            gload16(&X[(size_t)(r0 + row) * 512 + kt * 64 + chunk * 8], &Xa[flat * 8]);
        }
        #pragma unroll
        for (int i = 0; i < 2; ++i) {
            int flat = i * 256 + tid;
            int row = flat >> 3;
            int slot = flat & 7;
            int chunk = slot ^ (row & 7);
            gload16(&W[(size_t)row * 512 + kt * 64 + chunk * 8], &Wa[flat * 8]);
        }
        __syncthreads();

        #pragma unroll
        for (int ks = 0; ks < 2; ++ks) {
            short8 af[4], bfr[2];
            #pragma unroll
            for (int m = 0; m < 4; ++m) {
                int row = m * 16 + frow;
                int phys = (ks * 4 + kg) ^ (row & 7);
                af[m] = *(const short8*)&Wa[row * 64 + phys * 8];
            }
            #pragma unroll
            for (int n = 0; n < 2; ++n) {
                int row = w * 32 + n * 16 + frow;
                int phys = (ks * 4 + kg) ^ (row & 7);
                bfr[n] = *(const short8*)&Xa[row * 64 + phys * 8];
            }
            #pragma unroll
            for (int m = 0; m < 4; ++m)
                #pragma unroll
                for (int n = 0; n < 2; ++n)
                    acc[m][n] = __builtin_amdgcn_mfma_f32_16x16x32_bf16(af[m], bfr[n], acc[m][n], 0, 0, 0);
        }
        __syncthreads();
    }

    #pragma unroll
    for (int m = 0; m < 4; ++m) {
        #pragma unroll
        for (int n = 0; n < 2; ++n) {
            int r = r0 + w * 32 + n * 16 + frow;
            int b = r >> 12;
            int l = r & (LL - 1);
            int e = m * 16 + kg * 4;
            #pragma unroll
            for (int i = 0; i < 4; ++i)
                out[((size_t)b * NCH + e + i) * LL + l] = acc[m][n][i];
        }
    }
}

// ---------------- conv1d (width 4, taps l-1..l+2) + silu, bf16 in/out ----------------
// LDS row stride padded to 68 floats (272 B = +4 banks/row) to break the 4-way
// bank conflict of the 256 B power-of-2 stride.
__global__ void conv_silu(const unsigned short* __restrict__ xzb,
                          const float* __restrict__ wx, const float* __restrict__ wz,
                          unsigned short* __restrict__ xqb, unsigned short* __restrict__ ycb) {
    __shared__ float s[67][68];
    const int b = blockIdx.z;
    const int l0 = blockIdx.x * 64;
    const int c0 = blockIdx.y * 64;
    const int tid = threadIdx.x;
    for (int idx = tid; idx < 67 * 16; idx += 256) {
        int rr = idx >> 4, u = idx & 15;
        int l = l0 - 1 + rr;
        float4 f;
        if (l >= 0 && l < LL) {
            ushort4 v = *(const ushort4*)&xzb[((size_t)b * LL + l) * DINNER + c0 + u * 4];
            f = make_float4(bf2f(v.x), bf2f(v.y), bf2f(v.z), bf2f(v.w));
        } else f = make_float4(0.f, 0.f, 0.f, 0.f);
        *(float4*)&s[rr][u * 4] = f;
    }
    __syncthreads();
    const int ct = (tid & 15) * 4;       // 4 consecutive channels
    const int c = c0 + ct;
    const bool isx = (c < DHALF);
    const float* wp = isx ? &wx[c * 4] : &wz[(c - DHALF) * 4];
    float4 w0 = *(const float4*)&wp[0];
    float4 w1 = *(const float4*)&wp[4];
    float4 w2 = *(const float4*)&wp[8];
    float4 w3 = *(const float4*)&wp[12];
    #pragma unroll
    for (int rep = 0; rep < 4; ++rep) {
        int ll = (tid >> 4) + rep * 16;
        float4 t0 = *(const float4*)&s[ll][ct];
        float4 t1 = *(const float4*)&s[ll + 1][ct];
        float4 t2 = *(const float4*)&s[ll + 2][ct];
        float4 t3 = *(const float4*)&s[ll + 3][ct];
        float v0 = w0.x*t0.x + w0.y*t1.x + w0.z*t2.x + w0.w*t3.x;
        float v1 = w1.x*t0.y + w1.y*t1.y + w1.z*t2.y + w1.w*t3.y;
        float v2 = w2.x*t0.z + w2.y*t1.z + w2.z*t2.z + w2.w*t3.z;
        float v3 = w3.x*t0.w + w3.y*t1.w + w3.z*t2.w + w3.w*t3.w;
        ushort4 o = make_ushort4(f2bf(silu_f(v0)), f2bf(silu_f(v1)),
                                 f2bf(silu_f(v2)), f2bf(silu_f(v3)));
        int l = l0 + ll;
        if (isx) *(ushort4*)&xqb[((size_t)b * LL + l) * DHALF + c] = o;
        else     *(ushort4*)&ycb[((size_t)b * LL + l) * DINNER + c] = o;
    }
}

// ---------------- scan pass 1: fused dt + chunk-local scan -> (sdel, del, h_end) -------
// xdbl (b, 64, l): ch 0..31 = dt_rank rows, 32..47 = B, 48..63 = C
__global__ __launch_bounds__(256, 4) void scan1(const unsigned short* __restrict__ xqb,
                      const float* __restrict__ xdbl, const float* __restrict__ Arow2T,
                      const float* __restrict__ dtw, const float* __restrict__ dtb,
                      float* __restrict__ sdelb, float* __restrict__ delb,
                      float* __restrict__ hend) {
    __shared__ float s[48][CLEN];
    const int b = blockIdx.z;
    const int d = blockIdx.y * 256 + threadIdx.x;
    const int c = blockIdx.x;
    const int tid = threadIdx.x;
    for (int idx = tid; idx < 48 * CLEN; idx += 256) {
        int ch = idx >> 4, ll = idx & (CLEN - 1);
        s[ch][ll] = xdbl[((size_t)b * NCH + ch) * LL + c * CLEN + ll];
    }
    float dtwreg[RK];
    #pragma unroll
    for (int r = 0; r < RK; r += 4) {
        float4 v = *(const float4*)&dtw[d * RK + r];
        dtwreg[r] = v.x; dtwreg[r+1] = v.y; dtwreg[r+2] = v.z; dtwreg[r+3] = v.w;
    }
    float Arow2[DSTATE];
    #pragma unroll
    for (int n = 0; n < DSTATE; ++n) Arow2[n] = Arow2T[n * DHALF + d];   // coalesced
    const float bias = dtb[d];
    float del[CLEN];
    #pragma unroll
    for (int t = 0; t < CLEN; ++t) del[t] = bias;
    __syncthreads();
    #pragma unroll
    for (int r = 0; r < RK; ++r) {
        float wv = dtwreg[r];
        #pragma unroll
        for (int q = 0; q < CLEN / 4; ++q) {
            float4 v = *(const float4*)&s[r][q * 4];
            del[q*4+0] = fmaf(v.x, wv, del[q*4+0]);
            del[q*4+1] = fmaf(v.y, wv, del[q*4+1]);
            del[q*4+2] = fmaf(v.z, wv, del[q*4+2]);
            del[q*4+3] = fmaf(v.w, wv, del[q*4+3]);
        }
    }
    float sdel = 0.f;
    #pragma unroll
    for (int t = 0; t < CLEN; ++t) { del[t] = softplus_f(del[t]); sdel += del[t]; }
    size_t dbase = ((size_t)b * LL + c * CLEN) * DHALF + d;
    #pragma unroll
    for (int t = 0; t < CLEN; ++t) delb[dbase + (size_t)t * DHALF] = del[t];

    float h[DSTATE];
    #pragma unroll
    for (int n = 0; n < DSTATE; ++n) h[n] = 0.f;
    #pragma unroll
    for (int t = 0; t < CLEN; ++t) {
        float dl = del[t];
        float xv = bf2f(xqb[((size_t)b * LL + c * CLEN + t) * DHALF + d]);
        float dx = dl * xv;
        #pragma unroll
        for (int n = 0; n < DSTATE; ++n) {
            float dA = exp2_raw(dl * Arow2[n]);
            h[n] = fmaf(dA, h[n], dx * s[32 + n][t]);
        }
    }
    sdelb[((size_t)b * NC + c) * DHALF + d] = sdel;
    size_t base = (((size_t)b * NC + c) * DSTATE) * DHALF + d;
    #pragma unroll
    for (int n = 0; n < DSTATE; ++n)
        hend[base + (size_t)n * DHALF] = h[n];
}

// ---------------- scan2a: within-group prefix (hend in place) + group totals -----------
__global__ void scan2a(const float* __restrict__ sdelb, float* __restrict__ hend,
                       const float* __restrict__ Arow2T,
                       float* __restrict__ gP, float* __restrict__ gH) {
    int flat = blockIdx.x * 256 + threadIdx.x;   // B*NG*DSTATE*DHALF = 262144
    int d = flat & (DHALF - 1);
    int n = (flat >> 9) & (DSTATE - 1);
    int g = (flat >> 13) & (NG - 1);
    int b = flat >> 17;
    const float Arow2 = Arow2T[n * DHALF + d];
    const size_t stride = (size_t)DSTATE * DHALF;
    size_t idx = (((size_t)b * NC + g * GL) * DSTATE + n) * DHALF + d;
    size_t sidx = ((size_t)b * NC + g * GL) * DHALF + d;
    float S = 0.f, H = 0.f;
    #pragma unroll
    for (int j = 0; j < GL; ++j) {
        float sd = sdelb[sidx + (size_t)j * DHALF];
        float h = hend[idx];
        hend[idx] = H;            // store within-group carry-in
        H = fmaf(exp2_raw(Arow2 * sd), H, h);
        S += sd;
        idx += stride;
    }
    size_t gi = (((size_t)b * NG + g) * DSTATE + n) * DHALF + d;
    gP[gi] = exp2_raw(Arow2 * S);
    gH[gi] = H;
}

// ---------------- scan pass 3: load del, group-carry in-kernel, emit y -> ycb ----------
__global__ __launch_bounds__(256, 4) void scan3(const unsigned short* __restrict__ xqb,
                      const float* __restrict__ xdbl, const float* __restrict__ Arow2T,
                      const float* __restrict__ delb, const float* __restrict__ Dp,
                      const float* __restrict__ sdelb, const float* __restrict__ hend,
                      const float* __restrict__ gP, const float* __restrict__ gH,
                      unsigned short* __restrict__ ycb) {
    __shared__ float s[32][CLEN];       // B rows + C rows only
    const int b = blockIdx.z;
    const int d = blockIdx.y * 256 + threadIdx.x;
    const int c = blockIdx.x;
    const int tid = threadIdx.x;
    const int g = c / GL;
    for (int idx = tid; idx < 32 * CLEN; idx += 256) {
        int ch = 32 + (idx >> 4), ll = idx & (CLEN - 1);
        s[idx >> 4][ll] = xdbl[((size_t)b * NCH + ch) * LL + c * CLEN + ll];
    }
    float Arow2[DSTATE];
    #pragma unroll
    for (int n = 0; n < DSTATE; ++n) Arow2[n] = Arow2T[n * DHALF + d];

    // group carry: serial scan over groups 0..g-1 (uniform per block, coalesced loads)
    float Hcar[DSTATE];
    #pragma unroll
    for (int n = 0; n < DSTATE; ++n) Hcar[n] = 0.f;
    for (int gp = 0; gp < g; ++gp) {
        size_t gi = (((size_t)b * NG + gp) * DSTATE) * DHALF + d;
        #pragma unroll
        for (int n = 0; n < DSTATE; ++n)
            Hcar[n] = fmaf(gP[gi + (size_t)n * DHALF], Hcar[n], gH[gi + (size_t)n * DHALF]);
    }
    float Sc = 0.f;
    for (int j = g * GL; j < c; ++j)
        Sc += sdelb[((size_t)b * NC + j) * DHALF + d];

    float h[DSTATE];
    size_t base = (((size_t)b * NC + c) * DSTATE) * DHALF + d;
    #pragma unroll
    for (int n = 0; n < DSTATE; ++n)
        h[n] = fmaf(exp2_raw(Arow2[n] * Sc), Hcar[n], hend[base + (size_t)n * DHALF]);

    float del[CLEN];
    size_t dbase = ((size_t)b * LL + c * CLEN) * DHALF + d;
    #pragma unroll
    for (int t = 0; t < CLEN; ++t) del[t] = delb[dbase + (size_t)t * DHALF];

    const float Dv = Dp[d];
    __syncthreads();
    #pragma unroll
    for (int t = 0; t < CLEN; ++t) {
        float dl = del[t];
        float xv = bf2f(xqb[((size_t)b * LL + c * CLEN + t) * DHALF + d]);
        float dx = dl * xv;
        float y = Dv * xv;
        #pragma unroll
        for (int n = 0; n < DSTATE; ++n) {
            float dA = exp2_raw(dl * Arow2[n]);
            h[n] = fmaf(dA, h[n], dx * s[n][t]);          // B rows
            y = fmaf(h[n], s[16 + n][t], y);              // C rows
        }
        ycb[((size_t)b * LL + c * CLEN + t) * DINNER + d] = f2bf(y);
    }
}

extern "C" void kernel_launch(void* const* d_in, const int* in_sizes, int n_in,
                              void* d_out, int out_size, void* d_ws, size_t ws_size,
                              hipStream_t stream) {
    const float* hidden     = (const float*)d_in[0];
    const float* in_proj_w  = (const float*)d_in[1];
    const float* conv_x_w   = (const float*)d_in[2];
    const float* conv_z_w   = (const float*)d_in[3];
    const float* x_proj_w   = (const float*)d_in[4];
    const float* dt_proj_w  = (const float*)d_in[5];
    const float* dt_proj_b  = (const float*)d_in[6];
    const float* A_log      = (const float*)d_in[7];
    const float* Dp         = (const float*)d_in[8];
    const float* out_proj_w = (const float*)d_in[9];
    float* out = (float*)d_out;

    float* ws_f = (float*)d_ws;
    // float-unit offsets (sizes in floats)
    unsigned short* Wb  = (unsigned short*)(ws_f + 0);         // 262,144 f
    unsigned short* Wob = (unsigned short*)(ws_f + 262144);    // 262,144 f
    unsigned short* Wxb = (unsigned short*)(ws_f + 524288);    // 16,384 f
    unsigned short* Hb  = (unsigned short*)(ws_f + 540672);    // 2,097,152 f [cast->K1; then sdel]
    unsigned short* xzb = (unsigned short*)(ws_f + 2637824);   // 4,194,304 f [K1->conv; then hend]
    unsigned short* xqb = (unsigned short*)(ws_f + 6832128);   // 2,097,152 f bf16 (b,l,512)
    unsigned short* ycb = (unsigned short*)(ws_f + 8929280);   // 4,194,304 f bf16 (b,l,1024)
    float* xdbl   = ws_f + 13123584;                           // 524,288 f (b,64,l)
    float* gP     = ws_f + 13647872;                           // 262,144 f
    float* gH     = ws_f + 13910016;                           // 262,144 f
    float* Arow2T = ws_f + 14172160;                           // 8,192 f [16][512]
    float* delb   = ws_f + 14180352;                           // 4,194,304 f (B*L*DHALF)
    // aliases (dead regions at scan time):
    float* sdel = ws_f + 540672;                               // 262,144 f (over Hb)
    float* hend = ws_f + 2637824;                              // 4,194,304 f (over xzb)

    dim3 blk(256);

    // K0: casts + Arow2T precompute
    cast_all<<<dim3((H4 + W14 + W24 + W34 + NA + 255) / 256), blk, 0, stream>>>(
        hidden, in_proj_w, out_proj_w, x_proj_w, A_log, Hb, Wb, Wob, Wxb, Arow2T);
    // K1: in_proj (bf16 MFMA) -> xzb bf16 (b,l,1024)   [grid 64x16 = 1024 blocks]
    gemm_mfma<DMODEL, DINNER, true><<<dim3(BB * LL / 128, DINNER / 64), blk, 0, stream>>>(Wb, Hb, xzb);
    // K2: conv + silu -> xqb bf16; z-half -> ycb cols 512..1023
    conv_silu<<<dim3(LL / 64, DINNER / 64, BB), blk, 0, stream>>>(xzb, conv_x_w, conv_z_w, xqb, ycb);
    // K3: x_proj (bf16 MFMA) -> xdbl (b,64,l) fp32
    gemm_xproj<<<dim3(BB * LL / 128), blk, 0, stream>>>(Wxb, xqb, xdbl);
    // K5: fused dt + chunk-local scan  [Hb dead -> sdel; xzb dead -> hend]
    scan1<<<dim3(NC, DHALF / 256, BB), blk, 0, stream>>>(xqb, xdbl, Arow2T, dt_proj_w, dt_proj_b,
                                                         sdel, delb, hend);
    // K5b: within-group combine; group totals in gP/gH
    scan2a<<<dim3(BB * NG * DSTATE * DHALF / 256), blk, 0, stream>>>(sdel, hend, Arow2T, gP, gH);
    // K6: scan3 does group-carry + recompute with carry -> ycb bf16 cols 0..511
    scan3<<<dim3(NC, DHALF / 256, BB), blk, 0, stream>>>(xqb, xdbl, Arow2T, delb, Dp,
                                                         sdel, hend, gP, gH, ycb);
    // K7: out_proj (bf16 MFMA) -> out (b,l,512) fp32   [grid 64x8 = 512 blocks]
    gemm_mfma<DINNER, DMODEL, false><<<dim3(BB * LL / 128, DMODEL / 64), blk, 0, stream>>>(Wob, ycb, out);
}